// Round 1
// baseline (996.554 us; speedup 1.0000x reference)
//
#include <hip/hip_runtime.h>
#include <math.h>
#include <stdint.h>

// ---------------------------------------------------------------------------
// QuantizedLinear: out = x @ quantize(w)^T + bias
//   quantize(w) = clip(round(w/(mean|w|+eps)*h), -h, h),  h=(2^1.58-1)/2
//   Ternary trick: qw in {-h,0,+h} -> store t in {-1,0,+1} as EXACT bf16,
//   scale by h (fp32) in GEMM epilogue. Only x suffers bf16 rounding.
// Shapes: x[16384,4096] (M,K) fp32, w[4096,4096] (N,K) fp32, bias[4096],
//         out[16384,4096] fp32.  NT GEMM (both operands K-contiguous).
//
// R3: 256x256 8-phase GEMM (HK-style schedule in plain HIP).
//   R2 was the m97-structure (128^2 tile, __syncthreads per K-step): the
//   implicit vmcnt(0) drain before each barrier capped MfmaUtil at ~41%.
//   Here: 8 waves (2Mx4N), BK=64, 128 KiB LDS (2 dbuf x 2 half x {A,B}).
//   Each K-tile = 4 phases (one C-quadrant each): {12x ds_read_b128 ||
//   stage 1 half-tile via global_load_lds} -> s_barrier -> lgkmcnt(0) ->
//   setprio(1) + 16 MFMA -> s_barrier.  ONE s_waitcnt vmcnt(4) per K-tile
//   (never 0): 2 half-tiles stay in flight across every barrier.
//   Half-buffer ring: A-half/B-half slots free up mid-tile (quadrant order
//   (0,0),(0,1),(1,0),(1,1) -> A0 dead after P2, B0 after P3), so P3/P4
//   stage tile kt+2 into the CURRENT buffer safely.
//   LDS swizzle: slot (row,c) holds global chunk c^(row&7) (same scheme
//   that got R2 to 0 bank conflicts; 8 chunks x 4 banks, 2 lanes/bank).
//   XCD-bijective block swizzle (1024 blocks % 8 == 0).
// ---------------------------------------------------------------------------

#define MDIM 16384
#define NDIM 4096
#define KDIM 4096

// ---------------- reduction: sum |w| in double ----------------
__global__ void absmean_reduce(const float4* __restrict__ w4,
                               double* __restrict__ gsum, int n4) {
  int tid = blockIdx.x * blockDim.x + threadIdx.x;
  int stride = gridDim.x * blockDim.x;
  double s = 0.0;
  for (int i = tid; i < n4; i += stride) {
    float4 v = w4[i];
    s += (double)fabsf(v.x) + (double)fabsf(v.y) +
         (double)fabsf(v.z) + (double)fabsf(v.w);
  }
  for (int off = 32; off > 0; off >>= 1) s += __shfl_down(s, off, 64);
  __shared__ double partial[4];
  int ln = threadIdx.x & 63, wv = threadIdx.x >> 6;
  if (ln == 0) partial[wv] = s;
  __syncthreads();
  if (threadIdx.x == 0) {
    double t = partial[0] + partial[1] + partial[2] + partial[3];
    atomicAdd(gsum, t);
  }
}

// ---------------- quantize w -> ternary bf16 {-1,0,+1} ----------------
__device__ __forceinline__ unsigned short tern_bf16(float w, float g, float h) {
  float q = rintf(w / g * h);             // RNE, matches jnp.round
  q = fminf(fmaxf(q, -1.0f), 1.0f);       // {-2..2} -> {-1,0,1}
  return (unsigned short)(__float_as_uint(q) >> 16);  // ±1.0/±0.0 exact bf16
}

__global__ void quantize_w(const float4* __restrict__ w4,
                           const double* __restrict__ gsum,
                           ushort4* __restrict__ wq, int n4, float halfF) {
  const float gamma = (float)(*gsum * (1.0 / 16777216.0)) + 1e-8f;
  int tid = blockIdx.x * blockDim.x + threadIdx.x;
  int stride = gridDim.x * blockDim.x;
  for (int i = tid; i < n4; i += stride) {
    float4 v = w4[i];
    ushort4 o;
    o.x = tern_bf16(v.x, gamma, halfF);
    o.y = tern_bf16(v.y, gamma, halfF);
    o.z = tern_bf16(v.z, gamma, halfF);
    o.w = tern_bf16(v.w, gamma, halfF);
    wq[i] = o;
  }
}

// ---------------- convert x fp32 -> bf16 (RNE) ----------------
__device__ __forceinline__ unsigned bf16_rne(float f) {
  unsigned u = __float_as_uint(f);
  return (u + 0x7FFFu + ((u >> 16) & 1u)) >> 16;
}
__device__ __forceinline__ unsigned pack2(float lo, float hi) {
  return bf16_rne(lo) | (bf16_rne(hi) << 16);
}

__global__ void cvt_x(const float4* __restrict__ x4, uint4* __restrict__ xb,
                      int n8) {
  int tid = blockIdx.x * blockDim.x + threadIdx.x;
  int stride = gridDim.x * blockDim.x;
  for (int i = tid; i < n8; i += stride) {
    float4 a = x4[2 * i];
    float4 b = x4[2 * i + 1];
    uint4 o;
    o.x = pack2(a.x, a.y);
    o.y = pack2(a.z, a.w);
    o.z = pack2(b.x, b.y);
    o.w = pack2(b.z, b.w);
    xb[i] = o;
  }
}

// ---------------- GEMM: 256x256 tile, BK=64, 8-phase schedule ----------------
typedef __attribute__((ext_vector_type(8))) short bf16x8;  // 8 bf16 = 4 VGPRs
typedef __attribute__((ext_vector_type(4))) float f32x4;

#define BM 256
#define BN 256
#define BK 64
#define NTK (KDIM / BK)  // 64 K-tiles

__device__ __forceinline__ void async16(const short* g, short* l) {
  __builtin_amdgcn_global_load_lds(
      (const __attribute__((address_space(1))) unsigned int*)g,
      (__attribute__((address_space(3))) unsigned int*)l, 16, 0, 0);
}

__global__ __launch_bounds__(512, 2) void gemm_tern_256(
    const short* __restrict__ A,    // [M][K] bf16 bits (x)
    const short* __restrict__ Bw,   // [N][K] bf16 ternary (qw/h)
    const float* __restrict__ bias, // [N]
    float* __restrict__ out,        // [M][N] fp32
    float scale) {
  // LDS: buf(2) x { A-half0, A-half1, B-half0, B-half1 }, each 128x64 bf16.
  // shorts: half = 8192, buf stride = 32768, total 65536 shorts = 128 KiB.
  extern __shared__ short lds[];

  const int tid = threadIdx.x;
  const int wv = tid >> 6;   // 0..7
  const int ln = tid & 63;
  const int wr = wv >> 2;    // 0..1  (M group)
  const int wc = wv & 3;     // 0..3  (N group)
  const int l15 = ln & 15;
  const int lq = ln >> 4;    // 0..3
  const int l7 = ln & 7;

  // XCD-bijective block swizzle: nwg=1024, 8 XCDs, 128 blocks each.
  // Each XCD: one 8-tile M-band, sweeping all 16 N-tiles (A-panel L2 reuse).
  const int orig = blockIdx.x;
  const int wg = ((orig & 7) << 7) | (orig >> 3);
  const int bm = (wg >> 4) * BM;
  const int bn = (wg & 15) * BN;

  // ---- staging addressing (per thread, 2 global_load_lds per half-tile) ----
  // wave wv instruction ci covers rows grp*8..grp*8+7 of the 128-row half;
  // lane ln -> row +(ln>>3), LDS chunk ln&7; global chunk = (ln&7)^(row&7)
  // => LDS slot (row,c) holds global chunk c^(row&7).
  const int g8 = ln >> 3;
  const int sw = (l7 ^ (g8 & 7)) << 3;  // element offset within 64-elem row
  const int grp0 = wv * 2, grp1 = wv * 2 + 1;
  const short* aP0 = A + (size_t)(bm + grp0 * 8 + g8) * KDIM + sw;
  const short* aP1 = A + (size_t)(bm + grp1 * 8 + g8) * KDIM + sw;
  const short* bP0 = Bw + (size_t)(bn + grp0 * 8 + g8) * KDIM + sw;
  const short* bP1 = Bw + (size_t)(bn + grp1 * 8 + g8) * KDIM + sw;
  const int d0 = grp0 * 512, d1 = grp1 * 512;  // LDS dst (shorts) within half

  // ---- ds_read addressing ----
  // wave wr reads half-rows wr*64 + m*16 + (ln&15); chunk = (ks*4+lq)^(row&7)
  int rowA[4], rowB[2], chk[2];
#pragma unroll
  for (int m = 0; m < 4; ++m) rowA[m] = (wr * 64 + m * 16 + l15) * 64;
#pragma unroll
  for (int n = 0; n < 2; ++n) rowB[n] = (wc * 32 + n * 16 + l15) * 64;
#pragma unroll
  for (int ks = 0; ks < 2; ++ks) chk[ks] = (((ks * 4 + lq) ^ l7) << 3);

  f32x4 acc[2][2][4][2] = {};  // [mh][nh][m][n] -> 128 VGPRs

#define KOF(s) ((size_t)(((s) < NTK) ? (s) : 0) * BK)
#define STAGE_A(DST, H, S)                              \
  do {                                                  \
    const size_t koA_ = KOF(S) + (size_t)(H) * 128 * KDIM; \
    async16(aP0 + koA_, (DST) + (H) * 8192 + d0);       \
    async16(aP1 + koA_, (DST) + (H) * 8192 + d1);       \
  } while (0)
#define STAGE_B(DST, H, S)                                  \
  do {                                                      \
    const size_t koB_ = KOF(S) + (size_t)(H) * 128 * KDIM;  \
    async16(bP0 + koB_, (DST) + 16384 + (H) * 8192 + d0);   \
    async16(bP1 + koB_, (DST) + 16384 + (H) * 8192 + d1);   \
  } while (0)

  // ---- prologue (matches steady-state issue order) ----
  {
    short* b0 = lds;
    short* b1 = lds + 32768;
    STAGE_A(b0, 0, 0);
    STAGE_B(b0, 0, 0);
    STAGE_B(b0, 1, 0);
    STAGE_A(b0, 1, 0);
    STAGE_A(b1, 0, 1);
    STAGE_B(b1, 0, 1);
  }
  asm volatile("s_waitcnt vmcnt(4)" ::: "memory");  // tile0 landed; tile1 A0/B0 in flight
  __builtin_amdgcn_sched_barrier(0);
  __builtin_amdgcn_s_barrier();

  // phase = one C-quadrant (MH,NH): 12 ds_read_b128 + 1 half-tile stage,
  // raw barrier (NO vmcnt drain), lgkmcnt(0), 16 MFMA under setprio(1).
#define PHASE(MH, NH, STAGE_STMT, POST_STMT)                                  \
  do {                                                                        \
    bf16x8 fa[4][2], fb[2][2];                                                \
    const short* Ah_ = C + (MH) * 8192;                                       \
    const short* Bh_ = C + 16384 + (NH) * 8192;                               \
    _Pragma("unroll") for (int m = 0; m < 4; ++m) {                           \
      fa[m][0] = *(const bf16x8*)(Ah_ + rowA[m] + chk[0]);                    \
      fa[m][1] = *(const bf16x8*)(Ah_ + rowA[m] + chk[1]);                    \
    }                                                                         \
    _Pragma("unroll") for (int n = 0; n < 2; ++n) {                           \
      fb[n][0] = *(const bf16x8*)(Bh_ + rowB[n] + chk[0]);                    \
      fb[n][1] = *(const bf16x8*)(Bh_ + rowB[n] + chk[1]);                    \
    }                                                                         \
    STAGE_STMT;                                                               \
    __builtin_amdgcn_sched_barrier(0);                                        \
    __builtin_amdgcn_s_barrier();                                             \
    asm volatile("s_waitcnt lgkmcnt(0)" ::: "memory");                        \
    __builtin_amdgcn_sched_barrier(0);                                        \
    __builtin_amdgcn_s_setprio(1);                                            \
    _Pragma("unroll") for (int m = 0; m < 4; ++m)                             \
        _Pragma("unroll") for (int n = 0; n < 2; ++n) {                       \
      acc[MH][NH][m][n] = __builtin_amdgcn_mfma_f32_16x16x32_bf16(            \
          fa[m][0], fb[n][0], acc[MH][NH][m][n], 0, 0, 0);                    \
      acc[MH][NH][m][n] = __builtin_amdgcn_mfma_f32_16x16x32_bf16(            \
          fa[m][1], fb[n][1], acc[MH][NH][m][n], 0, 0, 0);                    \
    }                                                                         \
    __builtin_amdgcn_s_setprio(0);                                            \
    POST_STMT;                                                                \
    __builtin_amdgcn_sched_barrier(0);                                        \
    __builtin_amdgcn_s_barrier();                                             \
  } while (0)

  for (int kt = 0; kt < NTK; ++kt) {
    short* C = lds + ((kt & 1) << 15);          // current buffer
    short* Nx = lds + (((kt & 1) ^ 1) << 15);   // next buffer
    // P1 (0,0): reads C.A0,C.B0 | stage (kt+1).B1 (Nx.B1 dead since prev P4)
    PHASE(0, 0, STAGE_B(Nx, 1, kt + 1), ((void)0));
    // P2 (0,1): reads C.A0,C.B1 | stage (kt+1).A1
    PHASE(0, 1, STAGE_A(Nx, 1, kt + 1), ((void)0));
    // P3 (1,0): reads C.A1,C.B0 | stage (kt+2).A0 (C.A0 dead after P2)
    PHASE(1, 0, STAGE_A(C, 0, kt + 2), ((void)0));
    // P4 (1,1): reads C.A1,C.B1 | stage (kt+2).B0 (C.B0 dead after P3)
    // then vmcnt(4): (kt+1) halves all landed; (kt+2).A0/.B0 stay in flight.
    PHASE(1, 1, STAGE_B(C, 0, kt + 2),
          asm volatile("s_waitcnt vmcnt(4)" ::: "memory"));
  }

  // ---- epilogue: C/D layout col=ln&15, row=(ln>>4)*4+r (m89-verified) ----
  const int colb = bn + wc * 32 + l15;
  const int rowb = bm + wr * 64 + (lq << 2);
#pragma unroll
  for (int nh = 0; nh < 2; ++nh)
#pragma unroll
    for (int n = 0; n < 2; ++n) {
      const int col = colb + nh * 128 + n * 16;
      const float bj = bias[col];
#pragma unroll
      for (int mh = 0; mh < 2; ++mh)
#pragma unroll
        for (int m = 0; m < 4; ++m) {
          const int row = rowb + mh * 128 + m * 16;
#pragma unroll
          for (int r = 0; r < 4; ++r)
            out[(size_t)(row + r) * NDIM + col] =
                fmaf(acc[mh][nh][m][n][r], scale, bj);
        }
    }
}

// ---------------- launch ----------------
extern "C" void kernel_launch(void* const* d_in, const int* in_sizes, int n_in,
                              void* d_out, int out_size, void* d_ws,
                              size_t ws_size, hipStream_t stream) {
  const float* x = (const float*)d_in[0];     // [16384*4096]
  const float* w = (const float*)d_in[1];     // [4096*4096]
  const float* bias = (const float*)d_in[2];  // [4096]
  float* out = (float*)d_out;

  char* ws = (char*)d_ws;
  double* gsum = (double*)ws;                                // 8 B
  short* xb = (short*)(ws + 256);                            // 134 MB
  short* wq = (short*)(ws + 256 + (size_t)MDIM * KDIM * 2);  // 33.5 MB

  const float kHalfF = (float)((pow(2.0, 1.58) - 1.0) * 0.5);  // 0.99484926f

  static bool attr_done = false;
  if (!attr_done) {
    (void)hipFuncSetAttribute((const void*)gemm_tern_256,
                              hipFuncAttributeMaxDynamicSharedMemorySize,
                              131072);
    attr_done = true;
  }

  hipMemsetAsync(gsum, 0, sizeof(double), stream);

  const int nW4 = (NDIM * KDIM) / 4;
  absmean_reduce<<<1024, 256, 0, stream>>>((const float4*)w, gsum, nW4);

  quantize_w<<<4096, 256, 0, stream>>>((const float4*)w, gsum, (ushort4*)wq,
                                       nW4, kHalfF);

  const int nX8 = (MDIM * KDIM) / 8;
  cvt_x<<<8192, 256, 0, stream>>>((const float4*)x, (uint4*)xb, nX8);

  dim3 grid((MDIM / BM) * (NDIM / BN));  // 64 * 16 = 1024 blocks
  gemm_tern_256<<<grid, 512, 131072, stream>>>(xb, wq, bias, out, kHalfF);
}

// Round 2
// 939.582 us; speedup vs baseline: 1.0606x; 1.0606x over previous
//
#include <hip/hip_runtime.h>
#include <math.h>
#include <stdint.h>

// ---------------------------------------------------------------------------
// QuantizedLinear: out = x @ quantize(w)^T + bias
//   quantize(w) = clip(round(w/(mean|w|+eps)*h), -h, h),  h=(2^1.58-1)/2
//   Ternary trick: qw in {-h,0,+h} -> store t in {-1,0,+1} as EXACT bf16,
//   scale by h (fp32) in GEMM epilogue. Only x suffers bf16 rounding.
// Shapes: x[16384,4096] (M,K) fp32, w[4096,4096] (N,K) fp32, bias[4096],
//         out[16384,4096] fp32.  NT GEMM (both operands K-contiguous).
//
// R4: fragment reuse across phases (LDS-BW fix).
//   R3 (8-phase, 48 ds_read_b128/K-tile/wave) was LDS-read-BW bound:
//   384 KiB/K-tile / 256 B/clk = 1536 cyc vs 621 cyc MFMA -> 40% MfmaUtil
//   (measured 40.6%). Quadrant order (0,0),(0,1),(1,1),(1,0) + persistent
//   fragments: faA reloaded per A-half (8), fbB0/fbB1 loaded once per
//   K-tile (4 each) -> 24 reads/K-tile (12/4/8/0 per phase) -> cap ~80%.
//   Staging ring remapped to new slot liveness (A0,B0 dead after P1, B1
//   after P2, A1 after P3): P1->Nx.B1, P2->Nx.A1, P3->C.A0, P4->C.B0,
//   one s_waitcnt vmcnt(4) per K-tile (kt+1 landed, kt+2.A0/B0 in flight).
//   ds_read addresses: 4 per-lane base regs + compile-time offset:
//   immediates (frees rowA/rowB/chk regs to pay for +16 persistent fb).
// ---------------------------------------------------------------------------

#define MDIM 16384
#define NDIM 4096
#define KDIM 4096

// ---------------- reduction: sum |w| in double ----------------
__global__ void absmean_reduce(const float4* __restrict__ w4,
                               double* __restrict__ gsum, int n4) {
  int tid = blockIdx.x * blockDim.x + threadIdx.x;
  int stride = gridDim.x * blockDim.x;
  double s = 0.0;
  for (int i = tid; i < n4; i += stride) {
    float4 v = w4[i];
    s += (double)fabsf(v.x) + (double)fabsf(v.y) +
         (double)fabsf(v.z) + (double)fabsf(v.w);
  }
  for (int off = 32; off > 0; off >>= 1) s += __shfl_down(s, off, 64);
  __shared__ double partial[4];
  int ln = threadIdx.x & 63, wv = threadIdx.x >> 6;
  if (ln == 0) partial[wv] = s;
  __syncthreads();
  if (threadIdx.x == 0) {
    double t = partial[0] + partial[1] + partial[2] + partial[3];
    atomicAdd(gsum, t);
  }
}

// ---------------- quantize w -> ternary bf16 {-1,0,+1} ----------------
__device__ __forceinline__ unsigned short tern_bf16(float w, float g, float h) {
  float q = rintf(w / g * h);             // RNE, matches jnp.round
  q = fminf(fmaxf(q, -1.0f), 1.0f);       // {-2..2} -> {-1,0,1}
  return (unsigned short)(__float_as_uint(q) >> 16);  // ±1.0/±0.0 exact bf16
}

__global__ void quantize_w(const float4* __restrict__ w4,
                           const double* __restrict__ gsum,
                           ushort4* __restrict__ wq, int n4, float halfF) {
  const float gamma = (float)(*gsum * (1.0 / 16777216.0)) + 1e-8f;
  int tid = blockIdx.x * blockDim.x + threadIdx.x;
  int stride = gridDim.x * blockDim.x;
  for (int i = tid; i < n4; i += stride) {
    float4 v = w4[i];
    ushort4 o;
    o.x = tern_bf16(v.x, gamma, halfF);
    o.y = tern_bf16(v.y, gamma, halfF);
    o.z = tern_bf16(v.z, gamma, halfF);
    o.w = tern_bf16(v.w, gamma, halfF);
    wq[i] = o;
  }
}

// ---------------- convert x fp32 -> bf16 (RNE) ----------------
__device__ __forceinline__ unsigned bf16_rne(float f) {
  unsigned u = __float_as_uint(f);
  return (u + 0x7FFFu + ((u >> 16) & 1u)) >> 16;
}
__device__ __forceinline__ unsigned pack2(float lo, float hi) {
  return bf16_rne(lo) | (bf16_rne(hi) << 16);
}

__global__ void cvt_x(const float4* __restrict__ x4, uint4* __restrict__ xb,
                      int n8) {
  int tid = blockIdx.x * blockDim.x + threadIdx.x;
  int stride = gridDim.x * blockDim.x;
  for (int i = tid; i < n8; i += stride) {
    float4 a = x4[2 * i];
    float4 b = x4[2 * i + 1];
    uint4 o;
    o.x = pack2(a.x, a.y);
    o.y = pack2(a.z, a.w);
    o.z = pack2(b.x, b.y);
    o.w = pack2(b.z, b.w);
    xb[i] = o;
  }
}

// ---------------- GEMM: 256x256 tile, BK=64, 4-phase + frag reuse ----------
typedef __attribute__((ext_vector_type(8))) short bf16x8;  // 8 bf16 = 4 VGPRs
typedef __attribute__((ext_vector_type(4))) float f32x4;

#define BM 256
#define BN 256
#define BK 64
#define NTK (KDIM / BK)  // 64 K-tiles

__device__ __forceinline__ void async16(const short* g, short* l) {
  __builtin_amdgcn_global_load_lds(
      (const __attribute__((address_space(1))) unsigned int*)g,
      (__attribute__((address_space(3))) unsigned int*)l, 16, 0, 0);
}

__global__ __launch_bounds__(512, 2) void gemm_tern_256(
    const short* __restrict__ A,    // [M][K] bf16 bits (x)
    const short* __restrict__ Bw,   // [N][K] bf16 ternary (qw/h)
    const float* __restrict__ bias, // [N]
    float* __restrict__ out,        // [M][N] fp32
    float scale) {
  // LDS: buf(2) x { A-half0, A-half1, B-half0, B-half1 }, each 128x64 bf16.
  // shorts: half = 8192, B area = +16384, buf stride = 32768; 128 KiB total.
  extern __shared__ short lds[];

  const int tid = threadIdx.x;
  const int wv = tid >> 6;   // 0..7
  const int ln = tid & 63;
  const int wr = wv >> 2;    // 0..1  (M group)
  const int wc = wv & 3;     // 0..3  (N group)
  const int l15 = ln & 15;
  const int lq = ln >> 4;    // 0..3
  const int l7 = ln & 7;

  // XCD-bijective block swizzle: nwg=1024, 8 XCDs, 128 blocks each.
  const int orig = blockIdx.x;
  const int wg = ((orig & 7) << 7) | (orig >> 3);
  const int bm = (wg >> 4) * BM;
  const int bn = (wg & 15) * BN;

  // ---- staging addressing (2 global_load_lds per half-tile per wave) ----
  // LDS slot (row,c) holds global chunk c^(row&7) (bank-conflict-free, R2).
  const int g8 = ln >> 3;
  const int sw = (l7 ^ (g8 & 7)) << 3;  // swizzled global chunk offset
  const int grp0 = wv * 2, grp1 = wv * 2 + 1;
  const short* aP0 = A + (size_t)(bm + grp0 * 8 + g8) * KDIM + sw;
  const short* aP1 = A + (size_t)(bm + grp1 * 8 + g8) * KDIM + sw;
  const short* bP0 = Bw + (size_t)(bn + grp0 * 8 + g8) * KDIM + sw;
  const short* bP1 = Bw + (size_t)(bn + grp1 * 8 + g8) * KDIM + sw;
  const int d0 = grp0 * 512, d1 = grp1 * 512;  // LDS dst (shorts) within half

  // ---- ds_read lane offsets (shorts); per-frag deltas are immediates ----
  const int c0 = (lq ^ l7) << 3;         // chunk slot, k-slice 0
  const int c1 = ((4 + lq) ^ l7) << 3;   // chunk slot, k-slice 1
  const int aRow = (wr * 64 + l15) * 64;
  const int bRow = 16384 + (wc * 32 + l15) * 64;

  f32x4 acc[2][2][4][2] = {};            // [mh][nh][m][n] -> 128 AGPRs
  bf16x8 faA[4][2];                      // current A-half fragments
  bf16x8 fbB0[2][2], fbB1[2][2];         // B-half frags, live whole K-tile

#define KOF(s) ((size_t)(((s) < NTK) ? (s) : 0) * BK)
#define STAGE_A(DST, H, S)                                 \
  do {                                                     \
    const size_t koA_ = KOF(S) + (size_t)(H) * 128 * KDIM; \
    async16(aP0 + koA_, (DST) + (H) * 8192 + d0);          \
    async16(aP1 + koA_, (DST) + (H) * 8192 + d1);          \
  } while (0)
#define STAGE_B(DST, H, S)                                 \
  do {                                                     \
    const size_t koB_ = KOF(S) + (size_t)(H) * 128 * KDIM; \
    async16(bP0 + koB_, (DST) + 16384 + (H) * 8192 + d0);  \
    async16(bP1 + koB_, (DST) + 16384 + (H) * 8192 + d1);  \
  } while (0)

#define SYNC1                                            \
  __builtin_amdgcn_sched_barrier(0);                     \
  __builtin_amdgcn_s_barrier();                          \
  asm volatile("s_waitcnt lgkmcnt(0)" ::: "memory");     \
  __builtin_amdgcn_sched_barrier(0)

#define SYNC2                                            \
  __builtin_amdgcn_sched_barrier(0);                     \
  __builtin_amdgcn_s_barrier()

#define MFMA_QUAD(MH, NH, FB)                                        \
  do {                                                               \
    __builtin_amdgcn_s_setprio(1);                                   \
    _Pragma("unroll") for (int m = 0; m < 4; ++m)                    \
        _Pragma("unroll") for (int n = 0; n < 2; ++n) {              \
      acc[MH][NH][m][n] = __builtin_amdgcn_mfma_f32_16x16x32_bf16(   \
          faA[m][0], FB[n][0], acc[MH][NH][m][n], 0, 0, 0);          \
      acc[MH][NH][m][n] = __builtin_amdgcn_mfma_f32_16x16x32_bf16(   \
          faA[m][1], FB[n][1], acc[MH][NH][m][n], 0, 0, 0);          \
    }                                                                \
    __builtin_amdgcn_s_setprio(0);                                   \
  } while (0)

  // ---- prologue: tile0 all 4 halves, tile1 A0+B0; vmcnt(4) -> tile0 in ----
  {
    short* b0 = lds;
    short* b1 = lds + 32768;
    STAGE_A(b0, 0, 0);
    STAGE_B(b0, 0, 0);
    STAGE_B(b0, 1, 0);
    STAGE_A(b0, 1, 0);
    STAGE_A(b1, 0, 1);
    STAGE_B(b1, 0, 1);
  }
  asm volatile("s_waitcnt vmcnt(4)" ::: "memory");
  __builtin_amdgcn_sched_barrier(0);
  __builtin_amdgcn_s_barrier();

  for (int kt = 0; kt < NTK; ++kt) {
    const int curS = (kt & 1) << 15;
    short* Cb = lds + curS;            // current buffer
    short* Nx = lds + (curS ^ 32768);  // next buffer
    const short* a0 = Cb + aRow + c0;
    const short* a1 = Cb + aRow + c1;
    const short* b0 = Cb + bRow + c0;
    const short* b1 = Cb + bRow + c1;

    // -- P1 (0,0): load faA<-A0 (8), fbB0 (4) | stage (kt+1).B1 --
#pragma unroll
    for (int m = 0; m < 4; ++m) {
      faA[m][0] = *(const bf16x8*)(a0 + m * 1024);
      faA[m][1] = *(const bf16x8*)(a1 + m * 1024);
    }
#pragma unroll
    for (int n = 0; n < 2; ++n) {
      fbB0[n][0] = *(const bf16x8*)(b0 + n * 1024);
      fbB0[n][1] = *(const bf16x8*)(b1 + n * 1024);
    }
    STAGE_B(Nx, 1, kt + 1);
    SYNC1;
    MFMA_QUAD(0, 0, fbB0);
    SYNC2;

    // -- P2 (0,1): load fbB1 (4), reuse faA | stage (kt+1).A1 --
#pragma unroll
    for (int n = 0; n < 2; ++n) {
      fbB1[n][0] = *(const bf16x8*)(b0 + 8192 + n * 1024);
      fbB1[n][1] = *(const bf16x8*)(b1 + 8192 + n * 1024);
    }
    STAGE_A(Nx, 1, kt + 1);
    SYNC1;
    MFMA_QUAD(0, 1, fbB1);
    SYNC2;

    // -- P3 (1,1): load faA<-A1 (8), reuse fbB1 | stage (kt+2).A0 --
    //    (C.A0 slot dead since P1's reads)
#pragma unroll
    for (int m = 0; m < 4; ++m) {
      faA[m][0] = *(const bf16x8*)(a0 + 8192 + m * 1024);
      faA[m][1] = *(const bf16x8*)(a1 + 8192 + m * 1024);
    }
    STAGE_A(Cb, 0, kt + 2);
    SYNC1;
    MFMA_QUAD(1, 1, fbB1);
    SYNC2;

    // -- P4 (1,0): zero loads, reuse faA(A1) + fbB0 | stage (kt+2).B0 --
    //    vmcnt(4): kt+1 fully landed; kt+2.A0/B0 stay in flight.
    STAGE_B(Cb, 0, kt + 2);
    SYNC1;
    MFMA_QUAD(1, 0, fbB0);
    asm volatile("s_waitcnt vmcnt(4)" ::: "memory");
    SYNC2;
  }

  // ---- epilogue: C/D layout col=ln&15, row=(ln>>4)*4+r (m89-verified) ----
  const int colb = bn + wc * 32 + l15;
  const int rowb = bm + wr * 64 + (lq << 2);
#pragma unroll
  for (int nh = 0; nh < 2; ++nh)
#pragma unroll
    for (int n = 0; n < 2; ++n) {
      const int col = colb + nh * 128 + n * 16;
      const float bj = bias[col];
#pragma unroll
      for (int mh = 0; mh < 2; ++mh)
#pragma unroll
        for (int m = 0; m < 4; ++m) {
          const int row = rowb + mh * 128 + m * 16;
#pragma unroll
          for (int r = 0; r < 4; ++r)
            out[(size_t)(row + r) * NDIM + col] =
                fmaf(acc[mh][nh][m][n][r], scale, bj);
        }
    }
}

// ---------------- launch ----------------
extern "C" void kernel_launch(void* const* d_in, const int* in_sizes, int n_in,
                              void* d_out, int out_size, void* d_ws,
                              size_t ws_size, hipStream_t stream) {
  const float* x = (const float*)d_in[0];     // [16384*4096]
  const float* w = (const float*)d_in[1];     // [4096*4096]
  const float* bias = (const float*)d_in[2];  // [4096]
  float* out = (float*)d_out;

  char* ws = (char*)d_ws;
  double* gsum = (double*)ws;                                // 8 B
  short* xb = (short*)(ws + 256);                            // 134 MB
  short* wq = (short*)(ws + 256 + (size_t)MDIM * KDIM * 2);  // 33.5 MB

  const float kHalfF = (float)((pow(2.0, 1.58) - 1.0) * 0.5);  // 0.99484926f

  static bool attr_done = false;
  if (!attr_done) {
    (void)hipFuncSetAttribute((const void*)gemm_tern_256,
                              hipFuncAttributeMaxDynamicSharedMemorySize,
                              131072);
    attr_done = true;
  }

  hipMemsetAsync(gsum, 0, sizeof(double), stream);

  const int nW4 = (NDIM * KDIM) / 4;
  absmean_reduce<<<1024, 256, 0, stream>>>((const float4*)w, gsum, nW4);

  quantize_w<<<4096, 256, 0, stream>>>((const float4*)w, gsum, (ushort4*)wq,
                                       nW4, kHalfF);

  const int nX8 = (MDIM * KDIM) / 8;
  cvt_x<<<8192, 256, 0, stream>>>((const float4*)x, (uint4*)xb, nX8);

  dim3 grid((MDIM / BM) * (NDIM / BN));  // 64 * 16 = 1024 blocks
  gemm_tern_256<<<grid, 512, 131072, stream>>>(xb, wq, bias, out, kHalfF);
}